// Round 7
// baseline (54.690 us; speedup 1.0000x reference)
//
#include <hip/hip_runtime.h>
#include <hip/hip_fp16.h>

#define CROP_H 14
#define CROP_W 14
#define CROP_HW 196
#define CROP_HWP 98          // pairs per box
#define IMG_H 100
#define IMG_W 100
#define PLANE 10000
#define NCH 256
#define NBOX 512
#define NIMG 8

// d_ws layout:
//   geo_sorted : uint2[NBOX*CROP_HW]  (8 B per (slot,hw), sorted by image) @ 0
//   slot_of    : int[NBOX]                                                 @ GEO_BYTES
//   starts     : int[NIMG+1]                                               @ GEO_BYTES + NBOX*4
#define GEO_BYTES ((size_t)NBOX * CROP_HW * 8)
#define WS_NEED   (GEO_BYTES + NBOX * 4 + (NIMG + 1) * 4)

// ---------------- Kernel 1: stable bucket scan -> slot_of / starts ----------------
__global__ __launch_bounds__(64) void perm_kernel(
    const int* __restrict__ box_ind, int* __restrict__ slot_of, int* __restrict__ starts)
{
    const int t = threadIdx.x;
    int base = 0;
    for (int b = 0; b < NIMG; ++b) {
        if (t == 0) starts[b] = base;
        int nb = 0;
        for (int k = 0; k < NBOX / 64; ++k) {
            const int n = k * 64 + t;
            const bool m = (box_ind[n] == b);
            const unsigned long long mask = __ballot(m);
            if (m) slot_of[n] = base + nb + __popcll(mask & ((1ull << t) - 1ull));
            nb += __popcll(mask);
        }
        base += nb;   // uniform across lanes
    }
    if (t == 0) starts[NIMG] = base;
}

// ---------------- Kernel 2: geometry, written pre-sorted with n embedded ----------
// pk bits: [13:0]=tl offset, [14]=dx, [15]=dy, [16]=valid, [25:17]=n
__global__ __launch_bounds__(256) void geom_kernel(
    const float* __restrict__ boxes, const int* __restrict__ slot_of,
    uint2* __restrict__ geo)
{
    const int n = blockIdx.x;
    const int t = threadIdx.x;
    if (t >= CROP_HW) return;
    const int h = t / CROP_W;
    const int w = t - h * CROP_W;

    const float4 bx = reinterpret_cast<const float4*>(boxes)[n];
    const float y1 = bx.x, x1 = bx.y, y2 = bx.z, x2 = bx.w;

    const float scale_y = (y2 - y1) * (float)(IMG_H - 1) / (float)(CROP_H - 1);
    const float scale_x = (x2 - x1) * (float)(IMG_W - 1) / (float)(CROP_W - 1);

    const float in_y = y1 * (float)(IMG_H - 1) + (float)h * scale_y;
    const float in_x = x1 * (float)(IMG_W - 1) + (float)w * scale_x;

    const bool valid = (in_y >= 0.0f) & (in_y <= (float)(IMG_H - 1)) &
                       (in_x >= 0.0f) & (in_x <= (float)(IMG_W - 1));

    const float yc = fminf(fmaxf(in_y, 0.0f), (float)(IMG_H - 1));
    const float xc = fminf(fmaxf(in_x, 0.0f), (float)(IMG_W - 1));

    const float y0f = floorf(yc);
    const float x0f = floorf(xc);
    const float ly = yc - y0f;
    const float lx = xc - x0f;

    const int y0  = (int)y0f;
    const int x0  = (int)x0f;
    const int dy  = min(y0 + 1, IMG_H - 1) - y0;   // 0/1
    const int dx  = min(x0 + 1, IMG_W - 1) - x0;   // 0/1

    const unsigned pk = (unsigned)(y0 * IMG_W + x0)
                      | ((unsigned)dx << 14) | ((unsigned)dy << 15)
                      | (valid ? (1u << 16) : 0u) | ((unsigned)n << 17);

    const __half2 hh = __floats2half2_rn(lx, ly);
    const unsigned hbits = *reinterpret_cast<const unsigned*>(&hh);

    const int slot = slot_of[n];
    geo[slot * CROP_HW + t] = make_uint2(pk, hbits);
}

// ---------------- bilinear from LDS plane, packed geometry ----------------
__device__ __forceinline__ float bilerp(const float* __restrict__ s,
                                        unsigned pk, unsigned hbits)
{
    const int o   = (int)(pk & 0x3FFFu);
    const int dx  = (int)((pk >> 14) & 1u);
    const int dyo = (int)((pk >> 15) & 1u) * IMG_W;
    const __half2 h = *reinterpret_cast<const __half2*>(&hbits);
    const float lx = __low2float(h);
    const float ly = __high2float(h);
    const float wm = (pk & (1u << 16)) ? 1.0f : 0.0f;

    const float tl = s[o];
    const float tr = s[o + dx];
    const float bl = s[o + dyo];
    const float br = s[o + dyo + dx];

    const float top = tl + (tr - tl) * lx;
    const float bot = bl + (br - bl) * lx;
    return (top + (bot - top) * ly) * wm;
}

// ---------------- Kernel 3: one block per (b,c) plane; 512 thr; 4 blk/CU ----------
__global__ __launch_bounds__(512, 8) void crop_resize_main(
    const float* __restrict__ image,    // (8, 256, 100, 100)
    const int*   __restrict__ starts,   // [9]
    const uint2* __restrict__ geo,      // sorted, n embedded
    float* __restrict__ out)            // (512, 256, 14, 14)
{
    __shared__ float s_plane[PLANE];    // 40000 B -> 4 blocks/CU, 32 waves/CU

    const int blk = blockIdx.x;
    const int b   = blk >> 8;
    const int c   = blk & 255;
    const int t   = threadIdx.x;

    const float4* __restrict__ plane_g =
        reinterpret_cast<const float4*>(image + ((size_t)(b * NCH + c)) * PLANE);
    float4* __restrict__ s4 = reinterpret_cast<float4*>(s_plane);
    #pragma unroll
    for (int i = t; i < PLANE / 4; i += 512) s4[i] = plane_g[i];

    const int sb     = starts[b];
    const int totalp = (starts[b + 1] - sb) * CROP_HWP;   // pair units
    __syncthreads();

    const uint4* __restrict__ geo4 =
        reinterpret_cast<const uint4*>(geo) + (size_t)sb * CROP_HWP;
    float* __restrict__ outc = out + (size_t)c * CROP_HW;

    int p = t;
    if (p >= totalp) return;
    uint4 g = geo4[p];
    while (true) {
        const int pn = p + 512;
        uint4 gn = g;
        if (pn < totalp) gn = geo4[pn];        // prefetch next iteration

        const unsigned n = g.x >> 17;          // same for both packed entries
        const int hw = (p % CROP_HWP) * 2;

        const float v0 = bilerp(s_plane, g.x, g.y);
        const float v1 = bilerp(s_plane, g.z, g.w);

        float2 val = make_float2(v0, v1);
        unsigned long long bits = __builtin_bit_cast(unsigned long long, val);
        unsigned long long* dst = reinterpret_cast<unsigned long long*>(
            outc + (size_t)n * (NCH * CROP_HW) + hw);
        __builtin_nontemporal_store(bits, dst);

        if (pn >= totalp) break;
        g = gn;
        p = pn;
    }
}

// ---------------- Fallback (ws too small): known-good direct kernel ----------------
__global__ __launch_bounds__(256) void crop_resize_simple(
    const float* __restrict__ image, const float* __restrict__ boxes,
    const int* __restrict__ box_ind, float* __restrict__ out)
{
    const int n = blockIdx.y;
    const int i = blockIdx.x * 256 + threadIdx.x;
    const int c  = i / CROP_HW;
    const int hw = i - c * CROP_HW;
    const int h  = hw / CROP_W;
    const int w  = hw - h * CROP_W;

    const float y1 = boxes[n * 4 + 0];
    const float x1 = boxes[n * 4 + 1];
    const float y2 = boxes[n * 4 + 2];
    const float x2 = boxes[n * 4 + 3];
    const int   b  = box_ind[n];

    const float scale_y = (y2 - y1) * (float)(IMG_H - 1) / (float)(CROP_H - 1);
    const float scale_x = (x2 - x1) * (float)(IMG_W - 1) / (float)(CROP_W - 1);
    const float in_y = y1 * (float)(IMG_H - 1) + (float)h * scale_y;
    const float in_x = x1 * (float)(IMG_W - 1) + (float)w * scale_x;
    const bool valid = (in_y >= 0.0f) & (in_y <= (float)(IMG_H - 1)) &
                       (in_x >= 0.0f) & (in_x <= (float)(IMG_W - 1));
    const float yc = fminf(fmaxf(in_y, 0.0f), (float)(IMG_H - 1));
    const float xc = fminf(fmaxf(in_x, 0.0f), (float)(IMG_W - 1));
    const float y0f = floorf(yc), x0f = floorf(xc);
    const float ly = yc - y0f, lx = xc - x0f;
    const int y0 = (int)y0f, x0 = (int)x0f;
    const int y1i = min(y0 + 1, IMG_H - 1), x1i = min(x0 + 1, IMG_W - 1);

    const float* __restrict__ p = image + ((size_t)(b * NCH + c)) * PLANE;
    const float tl = p[y0  * IMG_W + x0];
    const float tr = p[y0  * IMG_W + x1i];
    const float bl = p[y1i * IMG_W + x0];
    const float br = p[y1i * IMG_W + x1i];
    const float top = tl + (tr - tl) * lx;
    const float bot = bl + (br - bl) * lx;
    float val = top + (bot - top) * ly;
    out[(size_t)n * (NCH * CROP_HW) + i] = valid ? val : 0.0f;
}

extern "C" void kernel_launch(void* const* d_in, const int* in_sizes, int n_in,
                              void* d_out, int out_size, void* d_ws, size_t ws_size,
                              hipStream_t stream) {
    const float* image   = (const float*)d_in[0];
    const float* boxes   = (const float*)d_in[1];
    const int*   box_ind = (const int*)d_in[2];
    float* out = (float*)d_out;

    if (ws_size < WS_NEED) {
        dim3 grid(196, NBOX);
        crop_resize_simple<<<grid, dim3(256), 0, stream>>>(image, boxes, box_ind, out);
        return;
    }

    uint2* geo    = (uint2*)d_ws;
    int*   slot_of = (int*)((char*)d_ws + GEO_BYTES);
    int*   starts  = slot_of + NBOX;

    perm_kernel<<<dim3(1), dim3(64), 0, stream>>>(box_ind, slot_of, starts);
    geom_kernel<<<dim3(NBOX), dim3(256), 0, stream>>>(boxes, slot_of, geo);
    crop_resize_main<<<dim3(NIMG * NCH), dim3(512), 0, stream>>>(image, starts, geo, out);
}